// Round 1
// 333.123 us; speedup vs baseline: 1.0351x; 1.0351x over previous
//
#include <hip/hip_runtime.h>
#include <hip/hip_bf16.h>

// Problem constants (from reference)
#define NN   2048      // B*S nodes
#define BB   16
#define SS   128
#define HH   256       // hidden
#define DE   192
#define DR   64
#define DIN  256
#define LOUT 12
#define NLEV 21
#define TE   127       // edges per tree (S-1), contiguous slice per tree

#define NT   16        // trees
#define CB   16        // col-blocks per tree
#define WC   16        // columns per block
#define RB   16        // row slots (256 threads = RB x WC)
#define CPAD 260       // padded row stride (float4-aligned)

// Sentinel: h = o*tanh(c) of finite inputs is always finite, so this NaN
// bit-pattern can never be produced by a publish. Pre-filled by phase1.
#define SENT64 0xFFFFFFFFFFFFFFFFULL

typedef unsigned long long ull;

__device__ __forceinline__ float sigm(float x){ return 1.f/(1.f + __expf(-x)); }

__device__ __forceinline__ ull pack2(float a, float b){
    union { float f[2]; ull u; } v; v.f[0] = a; v.f[1] = b; return v.u;
}
__device__ __forceinline__ void unpack2(ull u, float& a, float& b){
    union { ull u; float f[2]; } v; v.u = u; a = v.f[0]; b = v.f[1];
}
// relaxed agent-scope (device-coherent, cache-bypassing) accessors
__device__ __forceinline__ void st_dev(ull* p, ull v){
    __hip_atomic_store(p, v, __ATOMIC_RELAXED, __HIP_MEMORY_SCOPE_AGENT);
}
__device__ __forceinline__ ull ld_dev(const ull* p){
    return __hip_atomic_load(p, __ATOMIC_RELAXED, __HIP_MEMORY_SCOPE_AGENT);
}
__device__ __forceinline__ void st_devf(float* p, float v){
    __hip_atomic_store(p, v, __ATOMIC_RELAXED, __HIP_MEMORY_SCOPE_AGENT);
}
__device__ __forceinline__ int ld_devi(const int* p){
    return __hip_atomic_load(p, __ATOMIC_RELAXED, __HIP_MEMORY_SCOPE_AGENT);
}

// LDS-only barrier: waits DS ops but NOT in-flight global publish stores
// (vmcnt) -- removes the ~1 round-trip drain per barrier that the compiler's
// __syncthreads (vmcnt(0) lgkmcnt(0)) would impose. sched_barrier pins
// compiler motion; asm memory clobber orders memory ops.
__device__ __forceinline__ void barrier_lds(){
    __builtin_amdgcn_sched_barrier(0);
    asm volatile("s_waitcnt lgkmcnt(0)" ::: "memory");
    __builtin_amdgcn_s_barrier();
    __builtin_amdgcn_sched_barrier(0);
}

// Stage one producer's 16-col slice (8 ull = 64B) of a child h-row into LDS.
// Issues all 8 loads first (pipelined), then re-polls only sentinel words.
// The producer publishes the 8 words back-to-back, so usually one round.
__device__ __forceinline__ void stage_slice(const ull* __restrict__ src,
                                            float* __restrict__ dst16){
    ull u[8];
    #pragma unroll
    for (int q = 0; q < 8; ++q) u[q] = ld_dev(&src[q]);
    for (;;) {
        bool bad = false;
        #pragma unroll
        for (int q = 0; q < 8; ++q) bad = bad || (u[q] == SENT64);
        if (!bad) break;
        __builtin_amdgcn_s_sleep(1);
        #pragma unroll
        for (int q = 0; q < 8; ++q)
            if (u[q] == SENT64) u[q] = ld_dev(&src[q]);
    }
    #pragma unroll
    for (int q = 0; q < 4; ++q) {
        float4 v;
        unpack2(u[2*q],   v.x, v.y);
        unpack2(u[2*q+1], v.z, v.w);
        *(float4*)(dst16 + q*4) = v;
    }
}

// ---------------------------------------------------------------------------
// Phase 1: ix/fx/ox/ux = concat(emb,rel) @ W_* (+ b_*); 8 nodes/block. FP32.
// Each block also sentinel-fills its 8 nodes' h rows; block 0 sentinels
// poolbuf. (Agent-scope stores so tree_k's cache-bypassing polls see them.)
// ---------------------------------------------------------------------------
__global__ __launch_bounds__(256) void phase1_k(
    const int* __restrict__ xs, const int* __restrict__ rels,
    const float* __restrict__ emb_W, const float* __restrict__ rel_W,
    const float* __restrict__ W_ix, const float* __restrict__ b_ix,
    const float* __restrict__ W_fx, const float* __restrict__ b_fx,
    const float* __restrict__ W_ox, const float* __restrict__ W_ux,
    float* __restrict__ ix, float* __restrict__ fx,
    float* __restrict__ ox, float* __restrict__ ux,
    ull* __restrict__ hx, float* __restrict__ poolbuf)
{
    const int t = threadIdx.x;
    const int node0 = blockIdx.x * 8;
    __shared__ float xc[8][DIN];

    // sentinel-fill this block's 8 h rows (8 * 128 ull = 1024 words)
    {
        ull* hrow = hx + (long long)node0 * (HH/2);
        #pragma unroll
        for (int q = 0; q < 4; ++q)
            st_dev(&hrow[q*256 + t], SENT64);
    }
    if (blockIdx.x == 0) {
        int* pb = (int*)poolbuf;
        #pragma unroll
        for (int q = 0; q < (BB*HH)/256; ++q)
            __hip_atomic_store(&pb[q*256 + t], -1, __ATOMIC_RELAXED,
                               __HIP_MEMORY_SCOPE_AGENT);
    }

    #pragma unroll
    for (int j = 0; j < 8; ++j) {
        int n = node0 + j;
        if (t < DE) {
            long long w = (long long)xs[n];
            xc[j][t] = emb_W[w * DE + t];
        } else {
            long long r = (long long)rels[n];
            xc[j][t] = rel_W[r * DR + (t - DE)];
        }
    }
    __syncthreads();

    float ai[8], af[8], ao[8], au[8];
    const float bi  = b_ix[t];
    const float bfv = b_fx[t];
    #pragma unroll
    for (int j = 0; j < 8; ++j) { ai[j] = bi; af[j] = bfv; ao[j] = 0.f; au[j] = 0.f; }

    for (int k = 0; k < DIN; k += 4) {
        float wi[4], wf[4], wo[4], wu[4];
        #pragma unroll
        for (int q = 0; q < 4; ++q) {
            wi[q] = W_ix[(k+q)*HH + t];
            wf[q] = W_fx[(k+q)*HH + t];
            wo[q] = W_ox[(k+q)*HH + t];
            wu[q] = W_ux[(k+q)*HH + t];
        }
        #pragma unroll
        for (int j = 0; j < 8; ++j) {
            float4 xv = *(const float4*)&xc[j][k];
            ai[j] += xv.x*wi[0] + xv.y*wi[1] + xv.z*wi[2] + xv.w*wi[3];
            af[j] += xv.x*wf[0] + xv.y*wf[1] + xv.z*wf[2] + xv.w*wf[3];
            ao[j] += xv.x*wo[0] + xv.y*wo[1] + xv.z*wo[2] + xv.w*wo[3];
            au[j] += xv.x*wu[0] + xv.y*wu[1] + xv.z*wu[2] + xv.w*wu[3];
        }
    }
    #pragma unroll
    for (int j = 0; j < 8; ++j) {
        int n = node0 + j;
        ix[n*HH + t] = ai[j];
        fx[n*HH + t] = af[j];
        ox[n*HH + t] = ao[j];
        ux[n*HH + t] = au[j];
    }
}

// ---------------------------------------------------------------------------
// Fence-free fine-grained dataflow recurrence: 256 blocks = 16 trees x 16
// col-blocks, 1 block/CU (157KB LDS) => all co-resident on 256 CUs.
// No counters, no level barrier: consumers poll h-row words directly against
// the sentinel; producers publish straight from gate registers (shfl-pair ->
// 8B agent store) with no drain. Dependencies are strictly height-decreasing,
// so forward progress is guaranteed.
// ---------------------------------------------------------------------------
__global__ __launch_bounds__(256, 1) void tree_k(
    const int* __restrict__ child_idx, const int* __restrict__ parent_idx,
    const int* __restrict__ node_height,
    const float* __restrict__ W_ih, const float* __restrict__ b_ih,
    const float* __restrict__ W_fh, const float* __restrict__ b_fh,
    const float* __restrict__ W_oh, const float* __restrict__ W_uh,
    const float* __restrict__ ix, const float* __restrict__ fx,
    const float* __restrict__ ox, const float* __restrict__ ux,
    ull* __restrict__ hx, float* __restrict__ poolbuf,
    const float* __restrict__ W_out, const float* __restrict__ b_out,
    float* __restrict__ out)
{
    extern __shared__ float Wl[];            // [4][WC][CPAD] recurrent weights
    __shared__ float projL[4][SS][WC];       // ix,fx,ox,ux own-col slices
    __shared__ float cloc[SS][WC+1];         // cell state, never global
    __shared__ float hloc[SS][WC+1];         // own-col h, for pool
    __shared__ float hstage[RB][CPAD];
    __shared__ float hsN[RB][CPAD];
    __shared__ float part[3*RB][WC+1];
    __shared__ float fcN[RB][WC+1];
    __shared__ float biasF[WC], biasI[WC];
    __shared__ int loff[SS+1], lcur[SS], llist[SS];
    __shared__ int lvoff[NLEV+1], lvcur[NLEV], lvnodes[SS];
    __shared__ int chs[RB], slts[RB], csum[RB+1], nodes_s[RB];
    __shared__ int s_maxH;

    const int t   = threadIdx.x;
    const int bid = blockIdx.x;
    // XCD-affine: tree b's 16 blocks all have bid % 8 == b % 8 (perf only)
    const int xcd  = bid & 7;
    const int idx  = bid >> 3;               // 0..31
    const int b    = xcd + 8 * (idx >> 4);   // tree
    const int cgp  = idx & 15;               // col group
    const int col0 = cgp * WC;
    const int cc   = t & 15;
    const int rr   = t >> 4;                 // 0..15

    // ---- build this tree's CSR + level lists in LDS (local node ids) ----
    if (t < SS)   lcur[t]  = 0;
    if (t < NLEV) lvcur[t] = 0;
    if (t == 0)   s_maxH   = 0;
    __syncthreads();
    if (t < TE) { int p = parent_idx[b*TE + t] - b*SS; atomicAdd(&lcur[p], 1); }
    if (t < SS) { int hg = node_height[b*SS + t]; atomicAdd(&lvcur[hg], 1); atomicMax(&s_maxH, hg); }
    __syncthreads();
    if (t == 0) {
        int off = 0;
        for (int i = 0; i < SS; ++i) { int v = lcur[i]; loff[i] = off; lcur[i] = off; off += v; }
        loff[SS] = off;
        off = 0;
        for (int l = 0; l < NLEV; ++l) { int v = lvcur[l]; lvoff[l] = off; lvcur[l] = off; off += v; }
        lvoff[NLEV] = off;
    }
    __syncthreads();
    if (t < TE) {
        int e = b*TE + t;
        int p = parent_idx[e] - b*SS;
        int pos = atomicAdd(&lcur[p], 1);
        llist[pos] = child_idx[e] - b*SS;
    }
    if (t < SS) {
        int hg = node_height[b*SS + t];
        int pos = atomicAdd(&lvcur[hg], 1);
        lvnodes[pos] = t;
    }

    // ---- load recurrent weight slices into LDS (fh, ih, oh, uh) ----
    {
        const float* Wm[4] = { W_fh, W_ih, W_oh, W_uh };
        for (int m = 0; m < 4; ++m) {
            float* dst = Wl + (m*WC + cc)*CPAD;
            const float* src = Wm[m] + col0 + cc;
            #pragma unroll 4
            for (int kb = 0; kb < 16; ++kb) {
                int k = kb*16 + rr;
                dst[k] = src[(long long)k*HH];
            }
        }
        if (t < WC) { biasF[t] = b_fh[col0+t]; biasI[t] = b_ih[col0+t]; }
    }

    // ---- preload proj slices into LDS ----
    {
        const float* P[4] = { ix, fx, ox, ux };
        for (int m = 0; m < 4; ++m) {
            #pragma unroll
            for (int base = 0; base < 512; base += 256) {
                int i = base + t;                 // float4 index
                int n = i >> 2, q = i & 3;
                *(float4*)&projL[m][n][q*4] =
                    *(const float4*)&P[m][(long long)(b*SS + n)*HH + col0 + q*4];
            }
        }
    }
    __syncthreads();

    // ---- bottom-up levels (0 = leaves); no level-wide waits ----
    const int mH = s_maxH;
    for (int lev = 0; lev <= mH; ++lev) {
        const int s0 = lvoff[lev], s1 = lvoff[lev+1];

        if (lev > 0 && s1 - s0 == 1) {
            // ================= fast path: single node =================
            const int n  = lvnodes[s0];
            const int off = loff[n];
            const int E  = loff[n+1] - off;
            if (E <= RB) {
                if (t < E)  chs[t] = llist[off + t];
                if (t < WC) fcN[0][t] = 0.f;
                barrier_lds();
                // stage E child rows: thread (e, c2) polls one producer slice
                if (t < E*16) {
                    int e = t >> 4, c2 = t & 15;
                    stage_slice(hx + ((long long)(b*SS + chs[e]))*(HH/2) + c2*8,
                                &hstage[e][c2*16]);
                }
                barrier_lds();
                // hsum into hsN[0]
                {
                    float s = 0.f;
                    for (int e = 0; e < E; ++e) s += hstage[e][t];
                    hsN[0][t] = s;
                }
                barrier_lds();
                // dots: rows 0..E-1 = f per edge, E..E+2 = i/o/u on hsum.
                const int wv   = t >> 6;
                const int ksl4 = (t >> 4) & 3;
                const int nrows = E + 3;
                for (int p0 = 0; p0 < nrows; p0 += 4) {
                    int r = p0 + wv;
                    float d = 0.f;
                    if (r < nrows) {
                        const float* hr = (r < E) ? hstage[r] : hsN[0];
                        int mat = (r < E) ? 0 : (1 + (r - E));
                        const float* wm = Wl + (mat*WC + cc)*CPAD + ksl4*64;
                        const float* hh = hr + ksl4*64;
                        #pragma unroll 8
                        for (int k = 0; k < 64; k += 4) {
                            float4 w4 = *(const float4*)(wm + k);
                            float4 h4 = *(const float4*)(hh + k);
                            d += w4.x*h4.x + w4.y*h4.y + w4.z*h4.z + w4.w*h4.w;
                        }
                    }
                    d += __shfl_xor(d, 16);
                    d += __shfl_xor(d, 32);
                    if (r < nrows && ksl4 == 0) {
                        if (r < E) {
                            float f = sigm(d + biasF[cc] + projL[1][n][cc]);
                            atomicAdd(&fcN[0][cc], f * cloc[chs[r]][cc]);
                        } else {
                            part[r - E][cc] = d;
                        }
                    }
                }
                barrier_lds();
                if (t < WC) {
                    float iv = sigm(projL[0][n][t] + part[0][t] + biasI[t]);
                    float ov = sigm(projL[2][n][t] + part[1][t]);
                    float uv = tanhf(projL[3][n][t] + part[2][t]);
                    float cv = iv*uv + fcN[0][t];
                    float hv = ov * tanhf(cv);
                    cloc[n][t] = cv;
                    hloc[n][t] = hv;
                    // direct publish from registers: pair-pack via shfl
                    float hp = __shfl_xor(hv, 1);
                    if (!(t & 1))
                        st_dev(&hx[((long long)(b*SS + n))*(HH/2) + ((col0 + t) >> 1)],
                               pack2(hv, hp));
                }
                goto level_end;
            }
            // E > RB: fall through to generic path
        }

        for (int cs = s0; cs < s1; cs += RB) {
            const int nbN = min(RB, s1 - cs);

            if (lev == 0) {
                if (rr < nbN) {
                    int n = lvnodes[cs + rr];
                    float iv = sigm(projL[0][n][cc] + biasI[cc]);
                    float ov = sigm(projL[2][n][cc]);
                    float uv = tanhf(projL[3][n][cc]);
                    float cv = iv * uv;
                    float hv = ov * tanhf(cv);
                    cloc[n][cc] = cv;
                    hloc[n][cc] = hv;
                    float hp = __shfl_xor(hv, 1);
                    if (!(cc & 1))
                        st_dev(&hx[((long long)(b*SS + n))*(HH/2) + ((col0 + cc) >> 1)],
                               pack2(hv, hp));
                }
                continue;
            }

            if (t < nbN) {
                int n = lvnodes[cs + t];
                nodes_s[t] = n;
                csum[t+1]  = loff[n+1] - loff[n];
            }
            if (t == 0) csum[0] = 0;
            barrier_lds();
            if (t == 0) for (int i = 1; i <= nbN; ++i) csum[i] += csum[i-1];
            for (int r2 = 0; r2 < nbN; ++r2) hsN[r2][t] = 0.f;
            fcN[rr][cc] = 0.f;
            barrier_lds();

            const int Ech = csum[nbN];
            for (int eb = 0; eb < Ech; eb += RB) {
                const int m = min(RB, Ech - eb);
                if (t < m) {
                    int e = eb + t;
                    int s2 = 0;
                    while (csum[s2+1] <= e) ++s2;
                    chs[t]  = llist[loff[nodes_s[s2]] + (e - csum[s2])];
                    slts[t] = s2;
                }
                barrier_lds();
                // stage child h rows: sentinel-polled slices
                if (rr < m) {
                    stage_slice(hx + ((long long)(b*SS + chs[rr]))*(HH/2) + cc*8,
                                &hstage[rr][cc*16]);
                }
                barrier_lds();
                for (int jj = 0; jj < m; ++jj)
                    hsN[slts[jj]][t] += hstage[jj][t];
                const int nb = (m<=1)?1:(m<=2)?2:(m<=4)?4:(m<=8)?8:16;
                {
                    int slot = rr % nb;
                    int ksl  = rr / nb;
                    float d = 0.f;
                    if (slot < m) {
                        const float* wf = Wl + (0*WC + cc)*CPAD;
                        const float* hr = hstage[slot];
                        int k0 = ksl * (16*nb), k1 = k0 + 16*nb;
                        for (int k = k0; k < k1; k += 4) {
                            float4 w4 = *(const float4*)(wf + k);
                            float4 h4 = *(const float4*)(hr + k);
                            d += w4.x*h4.x + w4.y*h4.y + w4.z*h4.z + w4.w*h4.w;
                        }
                    }
                    part[rr][cc] = d;
                }
                barrier_lds();
                if (rr < m) {
                    float d = 0.f;
                    for (int j = rr; j < RB; j += nb) d += part[j][cc];
                    float f = sigm(d + biasF[cc] + projL[1][nodes_s[slts[rr]]][cc]);
                    atomicAdd(&fcN[slts[rr]][cc], f * cloc[chs[rr]][cc]);
                }
                barrier_lds();
            }

            // i/o/u dots over hsum, depth-adaptive
            {
                const int nb2 = (nbN<=1)?1:(nbN<=2)?2:(nbN<=4)?4:(nbN<=8)?8:16;
                int slot = rr % nb2;
                int ksl  = rr / nb2;
                int k0 = ksl * (16*nb2), k1 = k0 + 16*nb2;
                for (int mat = 0; mat < 3; ++mat) {
                    float d = 0.f;
                    if (slot < nbN) {
                        const float* wm = Wl + ((1+mat)*WC + cc)*CPAD;
                        const float* hr = hsN[slot];
                        for (int k = k0; k < k1; k += 4) {
                            float4 w4 = *(const float4*)(wm + k);
                            float4 h4 = *(const float4*)(hr + k);
                            d += w4.x*h4.x + w4.y*h4.y + w4.z*h4.z + w4.w*h4.w;
                        }
                    }
                    part[mat*RB + rr][cc] = d;
                }
                barrier_lds();
                if (rr < nbN) {
                    float di = 0.f, dof = 0.f, du = 0.f;
                    for (int j = rr; j < RB; j += nb2) {
                        di  += part[0*RB + j][cc];
                        dof += part[1*RB + j][cc];
                        du  += part[2*RB + j][cc];
                    }
                    int n = nodes_s[rr];
                    float iv = sigm(projL[0][n][cc] + di + biasI[cc]);
                    float ov = sigm(projL[2][n][cc] + dof);
                    float uv = tanhf(projL[3][n][cc] + du);
                    float cv = iv*uv + fcN[rr][cc];
                    float hv = ov * tanhf(cv);
                    cloc[n][cc] = cv;
                    hloc[n][cc] = hv;
                    float hp = __shfl_xor(hv, 1);
                    if (!(cc & 1))
                        st_dev(&hx[((long long)(b*SS + n))*(HH/2) + ((col0 + cc) >> 1)],
                               pack2(hv, hp));
                }
                barrier_lds();
            }
        }

level_end:
        barrier_lds();
    }

    // ---- max-pool own columns from LDS, exchange via sentinel poolbuf ----
    {
        float mx = -3.4e38f;
        for (int s2 = rr; s2 < SS; s2 += RB)
            mx = fmaxf(mx, hloc[s2][cc]);
        part[rr][cc] = mx;
        __syncthreads();
        if (t < WC) {
            float m2 = part[0][t];
            #pragma unroll
            for (int r2 = 1; r2 < RB; ++r2) m2 = fmaxf(m2, part[r2][t]);
            st_devf(&poolbuf[b*HH + col0 + t], m2);
        }
    }
    if (cgp == 0) {
        const int* pb = (const int*)poolbuf + b*HH + t;
        int w = ld_devi(pb);
        while (w == -1) { __builtin_amdgcn_s_sleep(1); w = ld_devi(pb); }
        float* pl = hstage[0];               // 260 >= 256 floats, reuse
        pl[t] = __int_as_float(w);
        __syncthreads();
        if (t < LOUT) {
            float acc = b_out[t];
            for (int k = 0; k < HH; ++k)
                acc += pl[k] * W_out[k*LOUT + t];
            out[b*LOUT + t] = acc;
        }
    }
}

// ---------------------------------------------------------------------------
extern "C" void kernel_launch(void* const* d_in, const int* in_sizes, int n_in,
                              void* d_out, int out_size, void* d_ws, size_t ws_size,
                              hipStream_t stream)
{
    const int* xs          = (const int*)d_in[0];
    const int* rels        = (const int*)d_in[1];
    const int* child_idx   = (const int*)d_in[2];
    const int* parent_idx  = (const int*)d_in[3];
    const int* node_height = (const int*)d_in[4];
    // d_in[5] = n_levels (hardcoded NLEV)
    const float* emb_W = (const float*)d_in[6];
    const float* rel_W = (const float*)d_in[7];
    const float* W_ix  = (const float*)d_in[8];
    const float* b_ix  = (const float*)d_in[9];
    const float* W_ih  = (const float*)d_in[10];
    const float* b_ih  = (const float*)d_in[11];
    const float* W_fx  = (const float*)d_in[12];
    const float* b_fx  = (const float*)d_in[13];
    const float* W_fh  = (const float*)d_in[14];
    const float* b_fh  = (const float*)d_in[15];
    const float* W_ox  = (const float*)d_in[16];
    const float* W_oh  = (const float*)d_in[17];
    const float* W_ux  = (const float*)d_in[18];
    const float* W_uh  = (const float*)d_in[19];
    const float* W_out = (const float*)d_in[20];
    const float* b_out = (const float*)d_in[21];

    const size_t NH = (size_t)NN * HH;
    float* ix = (float*)d_ws;
    float* fx = ix + NH;
    float* ox = fx + NH;
    float* ux = ox + NH;
    float* h  = ux + NH;                        // exchanged as ull pairs
    float* poolbuf = h + NH;                    // BB*HH floats

    phase1_k<<<NN/8, 256, 0, stream>>>(xs, rels, emb_W, rel_W,
                                       W_ix, b_ix, W_fx, b_fx, W_ox, W_ux,
                                       ix, fx, ox, ux,
                                       (ull*)h, poolbuf);

    const unsigned int shmem = 4u * WC * CPAD * sizeof(float);   // 66560 B
    tree_k<<<dim3(NT*CB), dim3(256), shmem, stream>>>(
        child_idx, parent_idx, node_height,
        W_ih, b_ih, W_fh, b_fh, W_oh, W_uh,
        ix, fx, ox, ux,
        (ull*)h, poolbuf,
        W_out, b_out, (float*)d_out);
}

// Round 2
// 261.987 us; speedup vs baseline: 1.3161x; 1.2715x over previous
//
#include <hip/hip_runtime.h>
#include <hip/hip_bf16.h>

// Problem constants (from reference)
#define NN   2048      // B*S nodes
#define BB   16
#define SS   128
#define HH   256       // hidden
#define DE   192
#define DR   64
#define DIN  256
#define LOUT 12
#define NLEV 21
#define TE   127       // edges per tree (S-1), contiguous slice per tree

#define NT   16        // trees
#define CB   16        // col-blocks per tree
#define WC   16        // columns per block
#define RB   16        // row slots (256 threads = RB x WC)
#define CPAD 260       // padded fp32 row stride (float4-aligned)
#define KP   264       // padded bf16 row stride (16B-aligned rows, 2-way banks)

// Sentinel: h = o*tanh(c) of finite inputs is always finite, so this NaN
// bit-pattern can never be produced by a publish. Pre-filled by phase1.
#define SENT64 0xFFFFFFFFFFFFFFFFULL

typedef unsigned long long ull;
typedef __attribute__((ext_vector_type(8))) short short8v;  // bf16x8 MFMA frag
typedef __attribute__((ext_vector_type(4))) float f32x4;    // MFMA accumulator

__device__ __forceinline__ float sigm(float x){ return 1.f/(1.f + __expf(-x)); }

__device__ __forceinline__ ull pack2(float a, float b){
    union { float f[2]; ull u; } v; v.f[0] = a; v.f[1] = b; return v.u;
}
__device__ __forceinline__ void unpack2(ull u, float& a, float& b){
    union { ull u; float f[2]; } v; v.u = u; a = v.f[0]; b = v.f[1];
}
__device__ __forceinline__ short f2bf(float f){
    union { __hip_bfloat16 b; short s; } v; v.b = __float2bfloat16(f); return v.s;
}
// relaxed agent-scope (device-coherent, cache-bypassing) accessors
__device__ __forceinline__ void st_dev(ull* p, ull v){
    __hip_atomic_store(p, v, __ATOMIC_RELAXED, __HIP_MEMORY_SCOPE_AGENT);
}
__device__ __forceinline__ ull ld_dev(const ull* p){
    return __hip_atomic_load(p, __ATOMIC_RELAXED, __HIP_MEMORY_SCOPE_AGENT);
}
__device__ __forceinline__ void st_devf(float* p, float v){
    __hip_atomic_store(p, v, __ATOMIC_RELAXED, __HIP_MEMORY_SCOPE_AGENT);
}
__device__ __forceinline__ int ld_devi(const int* p){
    return __hip_atomic_load(p, __ATOMIC_RELAXED, __HIP_MEMORY_SCOPE_AGENT);
}

// LDS-only barrier: waits DS ops but NOT in-flight global publish stores.
__device__ __forceinline__ void barrier_lds(){
    __builtin_amdgcn_sched_barrier(0);
    asm volatile("s_waitcnt lgkmcnt(0)" ::: "memory");
    __builtin_amdgcn_s_barrier();
    __builtin_amdgcn_sched_barrier(0);
}

// Stage one producer's 16-col slice (8 ull = 64B) of a child h-row into LDS.
__device__ __forceinline__ void stage_slice(const ull* __restrict__ src,
                                            float* __restrict__ dst16){
    ull u[8];
    #pragma unroll
    for (int q = 0; q < 8; ++q) u[q] = ld_dev(&src[q]);
    for (;;) {
        bool bad = false;
        #pragma unroll
        for (int q = 0; q < 8; ++q) bad = bad || (u[q] == SENT64);
        if (!bad) break;
        __builtin_amdgcn_s_sleep(1);
        #pragma unroll
        for (int q = 0; q < 8; ++q)
            if (u[q] == SENT64) u[q] = ld_dev(&src[q]);
    }
    #pragma unroll
    for (int q = 0; q < 4; ++q) {
        float4 v;
        unpack2(u[2*q],   v.x, v.y);
        unpack2(u[2*q+1], v.z, v.w);
        *(float4*)(dst16 + q*4) = v;
    }
}

// 16x16x256 bf16 matmul: D[row][col] = A[16][256] @ B[256][16] via 8 MFMAs.
// A rows indexed by lane&15; B is stored col-major [col][k] so its lane&15
// indexes the output column. D: col=lane&15, row=(lane>>4)*4+reg (m89-verified).
__device__ __forceinline__ f32x4 mm16(const short* __restrict__ A,
                                      const short* __restrict__ B, int lane){
    f32x4 acc = {0.f, 0.f, 0.f, 0.f};
    const int ro = (lane & 15) * KP + ((lane >> 4) << 3);
    #pragma unroll
    for (int k0 = 0; k0 < 256; k0 += 32)
        acc = __builtin_amdgcn_mfma_f32_16x16x32_bf16(
            *(const short8v*)(A + ro + k0),
            *(const short8v*)(B + ro + k0),
            acc, 0, 0, 0);
    return acc;
}

// ---------------------------------------------------------------------------
// Phase 1: ix/fx/ox/ux = concat(emb,rel) @ W_* (+ b_*); 8 nodes/block. FP32.
// ---------------------------------------------------------------------------
__global__ __launch_bounds__(256) void phase1_k(
    const int* __restrict__ xs, const int* __restrict__ rels,
    const float* __restrict__ emb_W, const float* __restrict__ rel_W,
    const float* __restrict__ W_ix, const float* __restrict__ b_ix,
    const float* __restrict__ W_fx, const float* __restrict__ b_fx,
    const float* __restrict__ W_ox, const float* __restrict__ W_ux,
    float* __restrict__ ix, float* __restrict__ fx,
    float* __restrict__ ox, float* __restrict__ ux,
    ull* __restrict__ hx, float* __restrict__ poolbuf)
{
    const int t = threadIdx.x;
    const int node0 = blockIdx.x * 8;
    __shared__ float xc[8][DIN];

    // sentinel-fill this block's 8 h rows (8 * 128 ull = 1024 words)
    {
        ull* hrow = hx + (long long)node0 * (HH/2);
        #pragma unroll
        for (int q = 0; q < 4; ++q)
            st_dev(&hrow[q*256 + t], SENT64);
    }
    if (blockIdx.x == 0) {
        int* pb = (int*)poolbuf;
        #pragma unroll
        for (int q = 0; q < (BB*HH)/256; ++q)
            __hip_atomic_store(&pb[q*256 + t], -1, __ATOMIC_RELAXED,
                               __HIP_MEMORY_SCOPE_AGENT);
    }

    #pragma unroll
    for (int j = 0; j < 8; ++j) {
        int n = node0 + j;
        if (t < DE) {
            long long w = (long long)xs[n];
            xc[j][t] = emb_W[w * DE + t];
        } else {
            long long r = (long long)rels[n];
            xc[j][t] = rel_W[r * DR + (t - DE)];
        }
    }
    __syncthreads();

    float ai[8], af[8], ao[8], au[8];
    const float bi  = b_ix[t];
    const float bfv = b_fx[t];
    #pragma unroll
    for (int j = 0; j < 8; ++j) { ai[j] = bi; af[j] = bfv; ao[j] = 0.f; au[j] = 0.f; }

    for (int k = 0; k < DIN; k += 4) {
        float wi[4], wf[4], wo[4], wu[4];
        #pragma unroll
        for (int q = 0; q < 4; ++q) {
            wi[q] = W_ix[(k+q)*HH + t];
            wf[q] = W_fx[(k+q)*HH + t];
            wo[q] = W_ox[(k+q)*HH + t];
            wu[q] = W_ux[(k+q)*HH + t];
        }
        #pragma unroll
        for (int j = 0; j < 8; ++j) {
            float4 xv = *(const float4*)&xc[j][k];
            ai[j] += xv.x*wi[0] + xv.y*wi[1] + xv.z*wi[2] + xv.w*wi[3];
            af[j] += xv.x*wf[0] + xv.y*wf[1] + xv.z*wf[2] + xv.w*wf[3];
            ao[j] += xv.x*wo[0] + xv.y*wo[1] + xv.z*wo[2] + xv.w*wo[3];
            au[j] += xv.x*wu[0] + xv.y*wu[1] + xv.z*wu[2] + xv.w*wu[3];
        }
    }
    #pragma unroll
    for (int j = 0; j < 8; ++j) {
        int n = node0 + j;
        ix[n*HH + t] = ai[j];
        fx[n*HH + t] = af[j];
        ox[n*HH + t] = ao[j];
        ux[n*HH + t] = au[j];
    }
}

// ---------------------------------------------------------------------------
// Fence-free fine-grained dataflow recurrence, MFMA edition.
// 256 blocks = 16 trees x 16 col-blocks, 1 block/CU => co-resident.
// All recurrent dots (f per edge; i/o/u per node) are 16x16x256 bf16 MFMAs:
// wave0 computes f, waves1-3 compute i/o/u concurrently. h publish/poll and
// hsum/c stay fp32; only dot INPUTS are rounded to bf16.
// ---------------------------------------------------------------------------
__global__ __launch_bounds__(256, 1) void tree_k(
    const int* __restrict__ child_idx, const int* __restrict__ parent_idx,
    const int* __restrict__ node_height,
    const float* __restrict__ W_ih, const float* __restrict__ b_ih,
    const float* __restrict__ W_fh, const float* __restrict__ b_fh,
    const float* __restrict__ W_oh, const float* __restrict__ W_uh,
    const float* __restrict__ ix, const float* __restrict__ fx,
    const float* __restrict__ ox, const float* __restrict__ ux,
    ull* __restrict__ hx, float* __restrict__ poolbuf,
    const float* __restrict__ W_out, const float* __restrict__ b_out,
    float* __restrict__ out)
{
    extern __shared__ short Wbf[];           // [4][WC][KP] bf16, col-major (row=cc)
    __shared__ float projL[4][SS][WC];       // ix,fx,ox,ux own-col slices
    __shared__ float cloc[SS][WC+1];         // cell state, never global
    __shared__ float hloc[SS][WC+1];         // own-col h, for pool
    __shared__ float hstage[RB][CPAD];       // staged child h rows (fp32)
    __shared__ float hsN[RB][CPAD];          // per-node h_sum (fp32)
    __shared__ __align__(16) short hstage_bf[RB][KP];  // bf16 A-frags (edges)
    __shared__ __align__(16) short hsN_bf[RB][KP];     // bf16 A-frags (h_sum)
    __shared__ float part[3*RB][WC+1];       // i/o/u dot outputs
    __shared__ float fcN[RB][WC+1];
    __shared__ float biasF[WC], biasI[WC];
    __shared__ int loff[SS+1], lcur[SS], llist[SS];
    __shared__ int lvoff[NLEV+1], lvcur[NLEV], lvnodes[SS];
    __shared__ int chs[RB], slts[RB], csum[RB+1], nodes_s[RB];
    __shared__ int s_maxH;

    const int t   = threadIdx.x;
    const int bid = blockIdx.x;
    // XCD-affine: tree b's 16 blocks all have bid % 8 == b % 8 (perf only)
    const int xcd  = bid & 7;
    const int idx  = bid >> 3;               // 0..31
    const int b    = xcd + 8 * (idx >> 4);   // tree
    const int cgp  = idx & 15;               // col group
    const int col0 = cgp * WC;
    const int cc   = t & 15;
    const int rr   = t >> 4;                 // 0..15

    // ---- build this tree's CSR + level lists in LDS (local node ids) ----
    if (t < SS)   lcur[t]  = 0;
    if (t < NLEV) lvcur[t] = 0;
    if (t == 0)   s_maxH   = 0;
    __syncthreads();
    if (t < TE) { int p = parent_idx[b*TE + t] - b*SS; atomicAdd(&lcur[p], 1); }
    if (t < SS) { int hg = node_height[b*SS + t]; atomicAdd(&lvcur[hg], 1); atomicMax(&s_maxH, hg); }
    __syncthreads();
    if (t == 0) {
        int off = 0;
        for (int i = 0; i < SS; ++i) { int v = lcur[i]; loff[i] = off; lcur[i] = off; off += v; }
        loff[SS] = off;
        off = 0;
        for (int l = 0; l < NLEV; ++l) { int v = lvcur[l]; lvoff[l] = off; lvcur[l] = off; off += v; }
        lvoff[NLEV] = off;
    }
    __syncthreads();
    if (t < TE) {
        int e = b*TE + t;
        int p = parent_idx[e] - b*SS;
        int pos = atomicAdd(&lcur[p], 1);
        llist[pos] = child_idx[e] - b*SS;
    }
    if (t < SS) {
        int hg = node_height[b*SS + t];
        int pos = atomicAdd(&lvcur[hg], 1);
        lvnodes[pos] = t;
    }

    // ---- load recurrent weight slices into LDS as bf16 (fh, ih, oh, uh) ----
    {
        const float* Wm[4] = { W_fh, W_ih, W_oh, W_uh };
        for (int m = 0; m < 4; ++m) {
            short* dst = Wbf + (m*WC + cc)*KP;
            const float* src = Wm[m] + col0 + cc;
            #pragma unroll 4
            for (int kb = 0; kb < 16; ++kb) {
                int k = kb*16 + rr;
                dst[k] = f2bf(src[(long long)k*HH]);
            }
        }
        if (t < WC) { biasF[t] = b_fh[col0+t]; biasI[t] = b_ih[col0+t]; }
    }

    // ---- preload proj slices into LDS ----
    {
        const float* P[4] = { ix, fx, ox, ux };
        for (int m = 0; m < 4; ++m) {
            #pragma unroll
            for (int base = 0; base < 512; base += 256) {
                int i = base + t;                 // float4 index
                int n = i >> 2, q = i & 3;
                *(float4*)&projL[m][n][q*4] =
                    *(const float4*)&P[m][(long long)(b*SS + n)*HH + col0 + q*4];
            }
        }
    }
    __syncthreads();

    // ---- bottom-up levels (0 = leaves); no level-wide waits ----
    const int mH = s_maxH;
    for (int lev = 0; lev <= mH; ++lev) {
        const int s0 = lvoff[lev], s1 = lvoff[lev+1];

        if (lev > 0 && s1 - s0 == 1) {
            // ================= fast path: single node =================
            const int n  = lvnodes[s0];
            const int off = loff[n];
            const int E  = loff[n+1] - off;
            if (E <= RB) {
                if (t < E)  chs[t] = llist[off + t];
                if (t < WC) fcN[0][t] = 0.f;
                barrier_lds();
                if (t < E*16) {
                    int e = t >> 4, c2 = t & 15;
                    stage_slice(hx + ((long long)(b*SS + chs[e]))*(HH/2) + c2*8,
                                &hstage[e][c2*16]);
                }
                barrier_lds();
                // convert child rows to bf16; hsum into hsN[0] (+bf16)
                for (int i = t; i < E*256; i += 256) {
                    int e = i >> 8, k = i & 255;
                    hstage_bf[e][k] = f2bf(hstage[e][k]);
                }
                {
                    float s = 0.f;
                    for (int e = 0; e < E; ++e) s += hstage[e][t];
                    hsN[0][t] = s;
                    hsN_bf[0][t] = f2bf(s);
                }
                barrier_lds();
                // 4 waves: wave0 = f-dots (rows=edges); waves1-3 = i/o/u (row 0)
                {
                    const int wv = t >> 6, lane = t & 63;
                    const int ccl = lane & 15, rbase = (lane >> 4) << 2;
                    if (wv == 0) {
                        f32x4 acc = mm16(&hstage_bf[0][0], Wbf, lane);
                        #pragma unroll
                        for (int r = 0; r < 4; ++r) {
                            int e = rbase + r;
                            if (e < E) {
                                float f = sigm(acc[r] + biasF[ccl] + projL[1][n][ccl]);
                                atomicAdd(&fcN[0][ccl], f * cloc[chs[e]][ccl]);
                            }
                        }
                    } else {
                        f32x4 acc = mm16(&hsN_bf[0][0], Wbf + (wv*WC)*KP, lane);
                        if (rbase == 0) part[(wv-1)*RB][ccl] = acc[0];
                    }
                }
                barrier_lds();
                if (t < WC) {
                    float iv = sigm(projL[0][n][t] + part[0*RB][t] + biasI[t]);
                    float ov = sigm(projL[2][n][t] + part[1*RB][t]);
                    float uv = tanhf(projL[3][n][t] + part[2*RB][t]);
                    float cv = iv*uv + fcN[0][t];
                    float hv = ov * tanhf(cv);
                    cloc[n][t] = cv;
                    hloc[n][t] = hv;
                    float hp = __shfl_xor(hv, 1);
                    if (!(t & 1))
                        st_dev(&hx[((long long)(b*SS + n))*(HH/2) + ((col0 + t) >> 1)],
                               pack2(hv, hp));
                }
                goto level_end;
            }
            // E > RB: fall through to generic path
        }

        for (int cs = s0; cs < s1; cs += RB) {
            const int nbN = min(RB, s1 - cs);

            if (lev == 0) {
                if (rr < nbN) {
                    int n = lvnodes[cs + rr];
                    float iv = sigm(projL[0][n][cc] + biasI[cc]);
                    float ov = sigm(projL[2][n][cc]);
                    float uv = tanhf(projL[3][n][cc]);
                    float cv = iv * uv;
                    float hv = ov * tanhf(cv);
                    cloc[n][cc] = cv;
                    hloc[n][cc] = hv;
                    float hp = __shfl_xor(hv, 1);
                    if (!(cc & 1))
                        st_dev(&hx[((long long)(b*SS + n))*(HH/2) + ((col0 + cc) >> 1)],
                               pack2(hv, hp));
                }
                continue;
            }

            if (t < nbN) {
                int n = lvnodes[cs + t];
                nodes_s[t] = n;
                csum[t+1]  = loff[n+1] - loff[n];
            }
            if (t == 0) csum[0] = 0;
            barrier_lds();
            if (t == 0) for (int i = 1; i <= nbN; ++i) csum[i] += csum[i-1];
            for (int r2 = 0; r2 < nbN; ++r2) hsN[r2][t] = 0.f;
            fcN[rr][cc] = 0.f;
            barrier_lds();

            const int Ech = csum[nbN];
            for (int eb = 0; eb < Ech; eb += RB) {
                const int m = min(RB, Ech - eb);
                if (t < m) {
                    int e = eb + t;
                    int s2 = 0;
                    while (csum[s2+1] <= e) ++s2;
                    chs[t]  = llist[loff[nodes_s[s2]] + (e - csum[s2])];
                    slts[t] = s2;
                }
                barrier_lds();
                // stage child h rows: sentinel-polled slices (fp32)
                if (rr < m) {
                    stage_slice(hx + ((long long)(b*SS + chs[rr]))*(HH/2) + cc*8,
                                &hstage[rr][cc*16]);
                }
                barrier_lds();
                // convert staged rows to bf16 + fp32 hsum accumulate
                for (int i = t; i < m*256; i += 256) {
                    int e = i >> 8, k = i & 255;
                    hstage_bf[e][k] = f2bf(hstage[e][k]);
                }
                for (int jj = 0; jj < m; ++jj)
                    hsN[slts[jj]][t] += hstage[jj][t];
                barrier_lds();
                // wave0: f-MFMA over all m edges + fc accumulation
                if (t < 64) {
                    const int lane = t, ccl = lane & 15, rbase = (lane >> 4) << 2;
                    f32x4 acc = mm16(&hstage_bf[0][0], Wbf, lane);
                    #pragma unroll
                    for (int r = 0; r < 4; ++r) {
                        int e = rbase + r;
                        if (e < m) {
                            float f = sigm(acc[r] + biasF[ccl]
                                           + projL[1][nodes_s[slts[e]]][ccl]);
                            atomicAdd(&fcN[slts[e]][ccl], f * cloc[chs[e]][ccl]);
                        }
                    }
                }
                barrier_lds();
            }

            // i/o/u dots over hsum via 3 concurrent MFMAs (waves 1-3)
            {
                for (int i = t; i < nbN*256; i += 256) {
                    int nd = i >> 8, k = i & 255;
                    hsN_bf[nd][k] = f2bf(hsN[nd][k]);
                }
                barrier_lds();
                {
                    const int wv = t >> 6, lane = t & 63;
                    if (wv >= 1) {
                        const int ccl = lane & 15, rbase = (lane >> 4) << 2;
                        f32x4 acc = mm16(&hsN_bf[0][0], Wbf + (wv*WC)*KP, lane);
                        #pragma unroll
                        for (int r = 0; r < 4; ++r)
                            part[(wv-1)*RB + rbase + r][ccl] = acc[r];
                    }
                }
                barrier_lds();
                if (rr < nbN) {
                    int n = nodes_s[rr];
                    float iv = sigm(projL[0][n][cc] + part[0*RB + rr][cc] + biasI[cc]);
                    float ov = sigm(projL[2][n][cc] + part[1*RB + rr][cc]);
                    float uv = tanhf(projL[3][n][cc] + part[2*RB + rr][cc]);
                    float cv = iv*uv + fcN[rr][cc];
                    float hv = ov * tanhf(cv);
                    cloc[n][cc] = cv;
                    hloc[n][cc] = hv;
                    float hp = __shfl_xor(hv, 1);
                    if (!(cc & 1))
                        st_dev(&hx[((long long)(b*SS + n))*(HH/2) + ((col0 + cc) >> 1)],
                               pack2(hv, hp));
                }
                barrier_lds();
            }
        }

level_end:
        barrier_lds();
    }

    // ---- max-pool own columns from LDS, exchange via sentinel poolbuf ----
    {
        float mx = -3.4e38f;
        for (int s2 = rr; s2 < SS; s2 += RB)
            mx = fmaxf(mx, hloc[s2][cc]);
        part[rr][cc] = mx;
        __syncthreads();
        if (t < WC) {
            float m2 = part[0][t];
            #pragma unroll
            for (int r2 = 1; r2 < RB; ++r2) m2 = fmaxf(m2, part[r2][t]);
            st_devf(&poolbuf[b*HH + col0 + t], m2);
        }
    }
    if (cgp == 0) {
        const int* pb = (const int*)poolbuf + b*HH + t;
        int w = ld_devi(pb);
        while (w == -1) { __builtin_amdgcn_s_sleep(1); w = ld_devi(pb); }
        float* pl = hstage[0];               // 260 >= 256 floats, reuse
        pl[t] = __int_as_float(w);
        __syncthreads();
        if (t < LOUT) {
            float acc = b_out[t];
            for (int k = 0; k < HH; ++k)
                acc += pl[k] * W_out[k*LOUT + t];
            out[b*LOUT + t] = acc;
        }
    }
}

// ---------------------------------------------------------------------------
extern "C" void kernel_launch(void* const* d_in, const int* in_sizes, int n_in,
                              void* d_out, int out_size, void* d_ws, size_t ws_size,
                              hipStream_t stream)
{
    const int* xs          = (const int*)d_in[0];
    const int* rels        = (const int*)d_in[1];
    const int* child_idx   = (const int*)d_in[2];
    const int* parent_idx  = (const int*)d_in[3];
    const int* node_height = (const int*)d_in[4];
    // d_in[5] = n_levels (hardcoded NLEV)
    const float* emb_W = (const float*)d_in[6];
    const float* rel_W = (const float*)d_in[7];
    const float* W_ix  = (const float*)d_in[8];
    const float* b_ix  = (const float*)d_in[9];
    const float* W_ih  = (const float*)d_in[10];
    const float* b_ih  = (const float*)d_in[11];
    const float* W_fx  = (const float*)d_in[12];
    const float* b_fx  = (const float*)d_in[13];
    const float* W_fh  = (const float*)d_in[14];
    const float* b_fh  = (const float*)d_in[15];
    const float* W_ox  = (const float*)d_in[16];
    const float* W_oh  = (const float*)d_in[17];
    const float* W_ux  = (const float*)d_in[18];
    const float* W_uh  = (const float*)d_in[19];
    const float* W_out = (const float*)d_in[20];
    const float* b_out = (const float*)d_in[21];

    const size_t NH = (size_t)NN * HH;
    float* ix = (float*)d_ws;
    float* fx = ix + NH;
    float* ox = fx + NH;
    float* ux = ox + NH;
    float* h  = ux + NH;                        // exchanged as ull pairs
    float* poolbuf = h + NH;                    // BB*HH floats

    phase1_k<<<NN/8, 256, 0, stream>>>(xs, rels, emb_W, rel_W,
                                       W_ix, b_ix, W_fx, b_fx, W_ox, W_ux,
                                       ix, fx, ox, ux,
                                       (ull*)h, poolbuf);

    const unsigned int shmem = 4u * WC * KP * sizeof(short);   // 33792 B
    tree_k<<<dim3(NT*CB), dim3(256), shmem, stream>>>(
        child_idx, parent_idx, node_height,
        W_ih, b_ih, W_fh, b_fh, W_oh, W_uh,
        ix, fx, ox, ux,
        (ull*)h, poolbuf,
        W_out, b_out, (float*)d_out);
}

// Round 3
// 235.191 us; speedup vs baseline: 1.4660x; 1.1139x over previous
//
#include <hip/hip_runtime.h>
#include <hip/hip_bf16.h>

// Problem constants (from reference)
#define NN   2048      // B*S nodes
#define BB   16
#define SS   128
#define HH   256       // hidden
#define DE   192
#define DR   64
#define DIN  256
#define LOUT 12
#define NLEV 21
#define TE   127       // edges per tree (S-1)

#define NT   16        // trees
#define CB   16        // col-blocks per tree
#define WC   16        // columns per block
#define RB   16        // node-chunk rows
#define EB   32        // edge-chunk rows
#define CPAD 260       // padded fp32 row stride
#define KP   264       // padded bf16 row stride (528B rows: 16B-aligned, bank-rotating)

// Sentinel: published h is finite => 4x bf16 NaN(0xFFFF) pattern is impossible.
#define SENT64 0xFFFFFFFFFFFFFFFFULL

typedef unsigned long long ull;
typedef __attribute__((ext_vector_type(8))) short short8v;  // bf16x8 MFMA frag
typedef __attribute__((ext_vector_type(4))) float f32x4;    // MFMA accumulator

__device__ __forceinline__ float sigm(float x){ return 1.f/(1.f + __expf(-x)); }

__device__ __forceinline__ short f2bf(float f){
    union { __hip_bfloat16 b; short s; } v; v.b = __float2bfloat16(f); return v.s;
}
__device__ __forceinline__ float bf2f(short s){
    union { unsigned u; float f; } v; v.u = ((unsigned)(unsigned short)s) << 16; return v.f;
}
// relaxed agent-scope (device-coherent, cache-bypassing) accessors
__device__ __forceinline__ void st_dev(ull* p, ull v){
    __hip_atomic_store(p, v, __ATOMIC_RELAXED, __HIP_MEMORY_SCOPE_AGENT);
}
__device__ __forceinline__ ull ld_dev(const ull* p){
    return __hip_atomic_load(p, __ATOMIC_RELAXED, __HIP_MEMORY_SCOPE_AGENT);
}
__device__ __forceinline__ void st_devf(float* p, float v){
    __hip_atomic_store(p, v, __ATOMIC_RELAXED, __HIP_MEMORY_SCOPE_AGENT);
}
__device__ __forceinline__ int ld_devi(const int* p){
    return __hip_atomic_load(p, __ATOMIC_RELAXED, __HIP_MEMORY_SCOPE_AGENT);
}

// LDS-only barrier: waits DS ops but NOT in-flight global publish stores.
__device__ __forceinline__ void barrier_lds(){
    __builtin_amdgcn_sched_barrier(0);
    asm volatile("s_waitcnt lgkmcnt(0)" ::: "memory");
    __builtin_amdgcn_s_barrier();
    __builtin_amdgcn_sched_barrier(0);
}

// Stage N ull (N*4 bf16 cols) of a child h-row: issue all, re-poll sentinels.
template<int N>
__device__ __forceinline__ void stageN(const ull* __restrict__ src,
                                       ull* __restrict__ dst){
    ull u[N];
    #pragma unroll
    for (int q = 0; q < N; ++q) u[q] = ld_dev(&src[q]);
    for (;;) {
        bool bad = false;
        #pragma unroll
        for (int q = 0; q < N; ++q) bad = bad || (u[q] == SENT64);
        if (!bad) break;
        __builtin_amdgcn_s_sleep(1);
        #pragma unroll
        for (int q = 0; q < N; ++q)
            if (u[q] == SENT64) u[q] = ld_dev(&src[q]);
    }
    #pragma unroll
    for (int q = 0; q < N; ++q) dst[q] = u[q];
}

// 16x16x256 bf16 matmul via 8 MFMAs. A rows / B cols indexed by lane&15;
// k-slot (lane>>4)*8. D: col=lane&15, row=(lane>>4)*4+reg (m89-verified).
__device__ __forceinline__ f32x4 mm16(const short* __restrict__ A,
                                      const short* __restrict__ B, int lane){
    f32x4 acc = {0.f, 0.f, 0.f, 0.f};
    const int ro = (lane & 15) * KP + ((lane >> 4) << 3);
    #pragma unroll
    for (int k0 = 0; k0 < 256; k0 += 32)
        acc = __builtin_amdgcn_mfma_f32_16x16x32_bf16(
            *(const short8v*)(A + ro + k0),
            *(const short8v*)(B + ro + k0),
            acc, 0, 0, 0);
    return acc;
}

// Pack 4 cols (bf16) from 4 adjacent lanes, store 1 ull (lane cc%4==0).
__device__ __forceinline__ void publish4(float hv, int cc, ull* rowp, int col0){
    unsigned p = (unsigned short)f2bf(hv);
    unsigned q = (unsigned)__shfl_xor((int)p, 1);
    unsigned pr = p | (q << 16);
    unsigned pr2 = (unsigned)__shfl_xor((int)pr, 2);
    if ((cc & 3) == 0)
        st_dev(rowp + ((col0 + cc) >> 2), pr | ((ull)pr2 << 32));
}

// ---------------------------------------------------------------------------
// Sentinel pre-fill (race-free: completes before tree_k starts, stream order)
// ---------------------------------------------------------------------------
__global__ __launch_bounds__(256) void fill_k(ull* __restrict__ hx,
                                              int* __restrict__ pb)
{
    const int t = threadIdx.x;
    const size_t base = (size_t)blockIdx.x * 512 + t;
    st_dev(&hx[base], SENT64);
    st_dev(&hx[base + 256], SENT64);
    if (blockIdx.x == 0) {
        #pragma unroll
        for (int q = 0; q < (BB*HH)/256; ++q)
            __hip_atomic_store(&pb[q*256 + t], -1, __ATOMIC_RELAXED,
                               __HIP_MEMORY_SCOPE_AGENT);
    }
}

// ---------------------------------------------------------------------------
// Single fused kernel: per-block x-gather + input projections (bf16 MFMA),
// then the fence-free dataflow recurrence (bf16 h exchange, fused phases).
// 256 blocks = 16 trees x 16 col-blocks, 1 block/CU => co-resident.
// ---------------------------------------------------------------------------
__global__ __launch_bounds__(256, 1) void tree_k(
    const int* __restrict__ xs, const int* __restrict__ rels,
    const float* __restrict__ emb_W, const float* __restrict__ rel_W,
    const float* __restrict__ W_ix, const float* __restrict__ b_ix,
    const float* __restrict__ W_fx, const float* __restrict__ b_fx,
    const float* __restrict__ W_ox, const float* __restrict__ W_ux,
    const int* __restrict__ child_idx, const int* __restrict__ parent_idx,
    const int* __restrict__ node_height,
    const float* __restrict__ W_ih, const float* __restrict__ b_ih,
    const float* __restrict__ W_fh, const float* __restrict__ b_fh,
    const float* __restrict__ W_oh, const float* __restrict__ W_uh,
    ull* __restrict__ hx, float* __restrict__ poolbuf,
    const float* __restrict__ W_out, const float* __restrict__ b_out,
    float* __restrict__ out)
{
    // ---- persistent LDS (static) ----
    __shared__ short Wbf[4*WC*KP];           // recurrent weights {fh,ih,oh,uh}, col-major
    __shared__ float projL[4][SS][WC];       // {ix,fx,ox,ux} own-col slices
    __shared__ float cloc[SS][WC+1];
    __shared__ float hloc[SS][WC+1];
    __shared__ float biasF[WC], biasI[WC];
    __shared__ int loff[SS+1], lcur[SS], llist[SS];
    __shared__ int lvoff[NLEV+1], lvcur[NLEV], lvnodes[SS];
    __shared__ int chs[EB], slts[EB], csum[RB+1], nodes_s[RB];
    __shared__ int s_maxH;
    // ---- transient LDS (dynamic, overlaid) ----
    extern __shared__ __align__(16) char trans[];
    short* xbf       = (short*)trans;                          // [SS][KP] (prologue)
    short* hstage_bf = (short*)trans;                          // [EB][KP]
    float* hsN       = (float*)(trans + EB*KP*2);              // [RB][CPAD]
    short* hsN_bf    = (short*)(trans + EB*KP*2 + RB*CPAD*4);  // [RB][KP]
    float* part      = (float*)(trans + EB*KP*2 + RB*CPAD*4 + RB*KP*2); // [3*RB][17]
    float* fcN       = part + 3*RB*17;                         // [RB][17]

    const int t    = threadIdx.x;
    const int bid  = blockIdx.x;
    const int xcd  = bid & 7;                // XCD-affine (perf only)
    const int idx  = bid >> 3;
    const int b    = xcd + 8 * (idx >> 4);   // tree
    const int cgp  = idx & 15;               // col group
    const int col0 = cgp * WC;
    const int cc   = t & 15;
    const int rr   = t >> 4;
    const int wv   = t >> 6;                 // wave id
    const int lane = t & 63;

    // ---- P0: stage xs/rels ints; zero counters ----
    if (t < SS) { llist[t] = xs[b*SS + t]; lvnodes[t] = rels[b*SS + t]; lcur[t] = 0; }
    if (t < NLEV) lvcur[t] = 0;
    if (t == 0)   s_maxH = 0;
    __syncthreads();

    // ---- P1: x-gather -> bf16 LDS (float4/lane); recurrent weights; biases ----
    for (int r = wv*32; r < wv*32 + 32; ++r) {
        float4 v;
        if (lane < 48) v = *(const float4*)&emb_W[(long long)llist[r]*DE + lane*4];
        else           v = *(const float4*)&rel_W[(long long)lvnodes[r]*DR + (lane-48)*4];
        union { short s[4]; ull u; } pk;
        pk.s[0] = f2bf(v.x); pk.s[1] = f2bf(v.y);
        pk.s[2] = f2bf(v.z); pk.s[3] = f2bf(v.w);
        *(ull*)&xbf[r*KP + lane*4] = pk.u;
    }
    {
        const float* Wm4[4] = { W_fh, W_ih, W_oh, W_uh };
        for (int m = 0; m < 4; ++m) {
            short* dst = Wbf + (m*WC + cc)*KP;
            const float* src = Wm4[m] + col0 + cc;
            #pragma unroll 4
            for (int kb = 0; kb < 16; ++kb) {
                int k = kb*16 + rr;
                dst[k] = f2bf(src[(long long)k*HH]);
            }
        }
        if (t < WC) { biasF[t] = b_fh[col0+t]; biasI[t] = b_ih[col0+t]; }
    }
    __syncthreads();

    // ---- P2: proj MFMA (wave m -> gate m) + CSR degree atomics ----
    if (t < TE) { int p = parent_idx[b*TE + t] - b*SS; atomicAdd(&lcur[p], 1); }
    if (t < SS) { int hg = node_height[b*SS + t]; atomicAdd(&lvcur[hg], 1); atomicMax(&s_maxH, hg); }
    {
        const float* Wxm = (wv==0) ? W_ix : (wv==1) ? W_fx : (wv==2) ? W_ox : W_ux;
        const int ccl = lane & 15, kg = lane >> 4;
        short8v bfr[8];
        #pragma unroll
        for (int f = 0; f < 8; ++f) {
            #pragma unroll
            for (int j = 0; j < 8; ++j)
                bfr[f][j] = f2bf(Wxm[(long long)(f*32 + kg*8 + j)*HH + col0 + ccl]);
        }
        const float bias = (wv==0) ? b_ix[col0+ccl] : (wv==1) ? b_fx[col0+ccl] : 0.f;
        for (int ch = 0; ch < 8; ++ch) {
            f32x4 acc = {0.f,0.f,0.f,0.f};
            const short* ap = xbf + (ch*16 + ccl)*KP + kg*8;
            #pragma unroll
            for (int f = 0; f < 8; ++f)
                acc = __builtin_amdgcn_mfma_f32_16x16x32_bf16(
                    *(const short8v*)(ap + f*32), bfr[f], acc, 0,0,0);
            #pragma unroll
            for (int r = 0; r < 4; ++r)
                projL[wv][ch*16 + kg*4 + r][ccl] = acc[r] + bias;
        }
    }
    __syncthreads();

    // ---- P3: CSR prefix sums ----
    if (t == 0) {
        int off = 0;
        for (int i = 0; i < SS; ++i) { int v = lcur[i]; loff[i] = off; lcur[i] = off; off += v; }
        loff[SS] = off;
        off = 0;
        for (int l2 = 0; l2 < NLEV; ++l2) { int v = lvcur[l2]; lvoff[l2] = off; lvcur[l2] = off; off += v; }
        lvoff[NLEV] = off;
    }
    __syncthreads();
    // ---- P4: CSR scatter (overwrites llist/lvnodes: x-gather is done) ----
    if (t < TE) {
        int e = b*TE + t;
        int p = parent_idx[e] - b*SS;
        int pos = atomicAdd(&lcur[p], 1);
        llist[pos] = child_idx[e] - b*SS;
    }
    if (t < SS) {
        int hg = node_height[b*SS + t];
        int pos = atomicAdd(&lvcur[hg], 1);
        lvnodes[pos] = t;
    }
    __syncthreads();

    // ---- bottom-up levels ----
    const int mH = s_maxH;
    for (int lev = 0; lev <= mH; ++lev) {
        const int s0 = lvoff[lev], s1 = lvoff[lev+1];
        int fastE = -1;
        if (lev > 0 && s1 - s0 == 1) {
            int n0 = lvnodes[s0];
            fastE = loff[n0+1] - loff[n0];
        }

        if (lev == 0) {
            for (int cs = s0; cs < s1; cs += RB) {
                int nbN = min(RB, s1 - cs);
                if (rr < nbN) {
                    int n = lvnodes[cs + rr];
                    float iv = sigm(projL[0][n][cc] + biasI[cc]);
                    float ov = sigm(projL[2][n][cc]);
                    float uv = tanhf(projL[3][n][cc]);
                    float cv = iv * uv;
                    float hv = ov * tanhf(cv);
                    cloc[n][cc] = cv; hloc[n][cc] = hv;
                    publish4(hv, cc, hx + (size_t)(b*SS + n)*64, col0);
                }
            }
        }
        else if (fastE > 0 && fastE <= RB) {
            // ============ fast path: single node, E<=16 ============
            const int n = lvnodes[s0];
            const int off = loff[n];
            const int E = fastE;
            if (t < E)  chs[t] = llist[off + t];
            if (t < WC) fcN[t] = 0.f;
            barrier_lds();
            if (rr < E)
                stageN<4>(hx + (size_t)(b*SS + chs[rr])*64 + cc*4,
                          (ull*)(hstage_bf + rr*KP + cc*16));
            barrier_lds();
            {
                const int ccl = lane & 15, kg = lane >> 4, rbase = kg << 2;
                if (wv == 0) {
                    f32x4 acc = mm16(hstage_bf, Wbf, lane);
                    #pragma unroll
                    for (int r = 0; r < 4; ++r) {
                        int e = rbase + r;
                        if (e < E) {
                            float f = sigm(acc[r] + biasF[ccl] + projL[1][n][ccl]);
                            atomicAdd(&fcN[ccl], f * cloc[chs[e]][ccl]);
                        }
                    }
                } else {
                    // in-register hsum (fp32 over bf16 children) + iou MFMA
                    f32x4 acc = {0.f,0.f,0.f,0.f};
                    const short* wm = Wbf + (wv*WC + ccl)*KP + kg*8;
                    for (int f = 0; f < 8; ++f) {
                        float s[8] = {0,0,0,0,0,0,0,0};
                        for (int e = 0; e < E; ++e) {
                            short8v xv = *(const short8v*)(hstage_bf + e*KP + f*32 + kg*8);
                            #pragma unroll
                            for (int j = 0; j < 8; ++j) s[j] += bf2f(xv[j]);
                        }
                        short8v af;
                        #pragma unroll
                        for (int j = 0; j < 8; ++j) af[j] = f2bf(s[j]);
                        acc = __builtin_amdgcn_mfma_f32_16x16x32_bf16(
                            af, *(const short8v*)(wm + f*32), acc, 0,0,0);
                    }
                    if (kg == 0) part[((wv-1)*RB)*17 + ccl] = acc[0];
                }
            }
            barrier_lds();
            if (t < WC) {
                float iv = sigm(projL[0][n][t] + part[0*17 + t] + biasI[t]);
                float ov = sigm(projL[2][n][t] + part[(1*RB)*17 + t]);
                float uv = tanhf(projL[3][n][t] + part[(2*RB)*17 + t]);
                float cv = iv*uv + fcN[t];
                float hv = ov * tanhf(cv);
                cloc[n][t] = cv; hloc[n][t] = hv;
                publish4(hv, t, hx + (size_t)(b*SS + n)*64, col0);
            }
        }
        else {
            // ============ generic path ============
            for (int cs = s0; cs < s1; cs += RB) {
                const int nbN = min(RB, s1 - cs);
                if (t < nbN) {
                    int n = lvnodes[cs + t];
                    nodes_s[t] = n;
                    csum[t+1] = loff[n+1] - loff[n];
                }
                if (t == 0) csum[0] = 0;
                barrier_lds();
                if (t == 0) for (int i = 1; i <= nbN; ++i) csum[i] += csum[i-1];
                for (int r2 = 0; r2 < nbN; ++r2) hsN[r2*CPAD + t] = 0.f;
                fcN[rr*17 + cc] = 0.f;
                barrier_lds();

                const int Ech = csum[nbN];
                for (int eb = 0; eb < Ech; eb += EB) {
                    const int m = min(EB, Ech - eb);
                    if (t < m) {
                        int e = eb + t;
                        int s2 = 0;
                        while (csum[s2+1] <= e) ++s2;
                        chs[t]  = llist[loff[nodes_s[s2]] + (e - csum[s2])];
                        slts[t] = s2;
                    }
                    barrier_lds();
                    if (m <= 16) {
                        if (rr < m)
                            stageN<4>(hx + (size_t)(b*SS + chs[rr])*64 + cc*4,
                                      (ull*)(hstage_bf + rr*KP + cc*16));
                    } else {
                        int row = t >> 3, q = t & 7;
                        if (row < m)
                            stageN<8>(hx + (size_t)(b*SS + chs[row])*64 + q*8,
                                      (ull*)(hstage_bf + row*KP + q*32));
                    }
                    barrier_lds();
                    const bool lastc = (eb + EB >= Ech);
                    if (wv < 2) {
                        // waves 0-1: f-MFMA over up to 32 edges + fc accumulate
                        if (wv*16 < m) {
                            const int ccl = lane & 15, rbase = (lane >> 4) << 2;
                            f32x4 acc = mm16(hstage_bf + wv*16*KP, Wbf, lane);
                            #pragma unroll
                            for (int r = 0; r < 4; ++r) {
                                int e = wv*16 + rbase + r;
                                if (e < m) {
                                    int sl = slts[e];
                                    float f = sigm(acc[r] + biasF[ccl]
                                                   + projL[1][nodes_s[sl]][ccl]);
                                    atomicAdd(&fcN[sl*17 + ccl],
                                              f * cloc[chs[e]][ccl]);
                                }
                            }
                        }
                    } else {
                        // waves 2-3: fp32 hsum accumulate (2 cols/thread)
                        const int kk = (t - 128) * 2;
                        float a0 = 0.f, a1 = 0.f;
                        int cur = slts[0];
                        for (int jj = 0; jj < m; ++jj) {
                            int s2 = slts[jj];
                            if (s2 != cur) {
                                hsN[cur*CPAD + kk]     += a0;
                                hsN[cur*CPAD + kk + 1] += a1;
                                a0 = a1 = 0.f; cur = s2;
                            }
                            unsigned v = *(const unsigned*)&hstage_bf[jj*KP + kk];
                            a0 += bf2f((short)(v & 0xFFFF));
                            a1 += bf2f((short)(v >> 16));
                        }
                        hsN[cur*CPAD + kk]     += a0;
                        hsN[cur*CPAD + kk + 1] += a1;
                        if (lastc) {
                            for (int s2 = 0; s2 < nbN; ++s2) {
                                hsN_bf[s2*KP + kk]     = f2bf(hsN[s2*CPAD + kk]);
                                hsN_bf[s2*KP + kk + 1] = f2bf(hsN[s2*CPAD + kk + 1]);
                            }
                        }
                    }
                    barrier_lds();
                }

                // i/o/u MFMAs (waves 1-3)
                if (wv >= 1) {
                    const int ccl = lane & 15, rbase = (lane >> 4) << 2;
                    f32x4 acc = mm16(hsN_bf, Wbf + (wv*WC)*KP, lane);
                    #pragma unroll
                    for (int r = 0; r < 4; ++r)
                        part[((wv-1)*RB + rbase + r)*17 + ccl] = acc[r];
                }
                barrier_lds();
                if (rr < nbN) {
                    int n = nodes_s[rr];
                    float iv = sigm(projL[0][n][cc] + part[(0*RB + rr)*17 + cc] + biasI[cc]);
                    float ov = sigm(projL[2][n][cc] + part[(1*RB + rr)*17 + cc]);
                    float uv = tanhf(projL[3][n][cc] + part[(2*RB + rr)*17 + cc]);
                    float cv = iv*uv + fcN[rr*17 + cc];
                    float hv = ov * tanhf(cv);
                    cloc[n][cc] = cv; hloc[n][cc] = hv;
                    publish4(hv, cc, hx + (size_t)(b*SS + n)*64, col0);
                }
                barrier_lds();
            }
        }
        barrier_lds();   // level end
    }

    // ---- max-pool own columns, exchange via sentinel poolbuf ----
    {
        float mx = -3.4e38f;
        for (int s2 = rr; s2 < SS; s2 += RB)
            mx = fmaxf(mx, hloc[s2][cc]);
        part[rr*17 + cc] = mx;
        __syncthreads();
        if (t < WC) {
            float m2 = part[0*17 + t];
            #pragma unroll
            for (int r2 = 1; r2 < RB; ++r2) m2 = fmaxf(m2, part[r2*17 + t]);
            st_devf(&poolbuf[b*HH + col0 + t], m2);
        }
    }
    if (cgp == 0) {
        const int* pb = (const int*)poolbuf + b*HH + t;
        int w = ld_devi(pb);
        while (w == -1) { __builtin_amdgcn_s_sleep(1); w = ld_devi(pb); }
        float* pl = (float*)trans;           // recurrence done; reuse
        pl[t] = __int_as_float(w);
        __syncthreads();
        if (t < LOUT) {
            float acc = b_out[t];
            for (int k = 0; k < HH; ++k)
                acc += pl[k] * W_out[k*LOUT + t];
            out[b*LOUT + t] = acc;
        }
    }
}

// ---------------------------------------------------------------------------
extern "C" void kernel_launch(void* const* d_in, const int* in_sizes, int n_in,
                              void* d_out, int out_size, void* d_ws, size_t ws_size,
                              hipStream_t stream)
{
    const int* xs          = (const int*)d_in[0];
    const int* rels        = (const int*)d_in[1];
    const int* child_idx   = (const int*)d_in[2];
    const int* parent_idx  = (const int*)d_in[3];
    const int* node_height = (const int*)d_in[4];
    // d_in[5] = n_levels (hardcoded NLEV)
    const float* emb_W = (const float*)d_in[6];
    const float* rel_W = (const float*)d_in[7];
    const float* W_ix  = (const float*)d_in[8];
    const float* b_ix  = (const float*)d_in[9];
    const float* W_ih  = (const float*)d_in[10];
    const float* b_ih  = (const float*)d_in[11];
    const float* W_fx  = (const float*)d_in[12];
    const float* b_fx  = (const float*)d_in[13];
    const float* W_fh  = (const float*)d_in[14];
    const float* b_fh  = (const float*)d_in[15];
    const float* W_ox  = (const float*)d_in[16];
    const float* W_oh  = (const float*)d_in[17];
    const float* W_ux  = (const float*)d_in[18];
    const float* W_uh  = (const float*)d_in[19];
    const float* W_out = (const float*)d_in[20];
    const float* b_out = (const float*)d_in[21];

    ull*   hx      = (ull*)d_ws;                         // NN*64 ull = 1 MB
    float* poolbuf = (float*)((char*)d_ws + (size_t)NN*64*8);  // BB*HH floats

    fill_k<<<256, 256, 0, stream>>>(hx, (int*)poolbuf);

    const unsigned int shmem = (unsigned int)(SS * KP * 2);   // 67584 B transient
    tree_k<<<dim3(NT*CB), dim3(256), shmem, stream>>>(
        xs, rels, emb_W, rel_W,
        W_ix, b_ix, W_fx, b_fx, W_ox, W_ux,
        child_idx, parent_idx, node_height,
        W_ih, b_ih, W_fh, b_fh, W_oh, W_uh,
        hx, poolbuf,
        W_out, b_out, (float*)d_out);
}

// Round 4
// 229.720 us; speedup vs baseline: 1.5010x; 1.0238x over previous
//
#include <hip/hip_runtime.h>
#include <hip/hip_bf16.h>

// Problem constants (from reference)
#define NN   2048      // B*S nodes
#define BB   16
#define SS   128
#define HH   256       // hidden
#define DE   192
#define DR   64
#define DIN  256
#define LOUT 12
#define NLEV 21
#define TE   127       // edges per tree (S-1)

#define NT   16        // trees
#define CB   16        // col-blocks per tree
#define WC   16        // columns per block
#define RB   16
#define KP   264       // padded bf16 row stride (528B rows, 16B-aligned, bank-rotating)

// Sentinel: published h is finite => 4x bf16 NaN(0xFFFF) pattern is impossible.
#define SENT64 0xFFFFFFFFFFFFFFFFULL

typedef unsigned long long ull;
typedef __attribute__((ext_vector_type(8))) short short8v;  // bf16x8 MFMA frag
typedef __attribute__((ext_vector_type(4))) float f32x4;    // MFMA accumulator

__device__ __forceinline__ float sigm(float x){ return 1.f/(1.f + __expf(-x)); }

__device__ __forceinline__ short f2bf(float f){
    union { __hip_bfloat16 b; short s; } v; v.b = __float2bfloat16(f); return v.s;
}
__device__ __forceinline__ float bf2f(short s){
    union { unsigned u; float f; } v; v.u = ((unsigned)(unsigned short)s) << 16; return v.f;
}
// relaxed agent-scope (device-coherent, cache-bypassing) accessors
__device__ __forceinline__ void st_dev(ull* p, ull v){
    __hip_atomic_store(p, v, __ATOMIC_RELAXED, __HIP_MEMORY_SCOPE_AGENT);
}
__device__ __forceinline__ ull ld_dev(const ull* p){
    return __hip_atomic_load(p, __ATOMIC_RELAXED, __HIP_MEMORY_SCOPE_AGENT);
}
__device__ __forceinline__ void st_devf(float* p, float v){
    __hip_atomic_store(p, v, __ATOMIC_RELAXED, __HIP_MEMORY_SCOPE_AGENT);
}
__device__ __forceinline__ int ld_devi(const int* p){
    return __hip_atomic_load(p, __ATOMIC_RELAXED, __HIP_MEMORY_SCOPE_AGENT);
}

// LDS-only barrier: waits DS ops but NOT in-flight global publish stores.
__device__ __forceinline__ void barrier_lds(){
    __builtin_amdgcn_sched_barrier(0);
    asm volatile("s_waitcnt lgkmcnt(0)" ::: "memory");
    __builtin_amdgcn_s_barrier();
    __builtin_amdgcn_sched_barrier(0);
}

// Pack 4 cols (bf16) from 4 adjacent lanes, store 1 ull (lanes with cc%4==0).
__device__ __forceinline__ void publish4(float hv, int cc, ull* rowp, int col0){
    unsigned p = (unsigned short)f2bf(hv);
    unsigned q = (unsigned)__shfl_xor((int)p, 1);
    unsigned pr = p | (q << 16);
    unsigned pr2 = (unsigned)__shfl_xor((int)pr, 2);
    if ((cc & 3) == 0)
        st_dev(rowp + ((col0 + cc) >> 2), pr | ((ull)pr2 << 32));
}

// ---------------------------------------------------------------------------
// Sentinel pre-fill (race-free: completes before tree_k starts, stream order)
// ---------------------------------------------------------------------------
__global__ __launch_bounds__(256) void fill_k(ull* __restrict__ hx,
                                              int* __restrict__ pb)
{
    const int t = threadIdx.x;
    const size_t base = (size_t)blockIdx.x * 512 + t;
    st_dev(&hx[base], SENT64);
    st_dev(&hx[base + 256], SENT64);
    if (blockIdx.x == 0) {
        #pragma unroll
        for (int q = 0; q < (BB*HH)/256; ++q)
            __hip_atomic_store(&pb[q*256 + t], -1, __ATOMIC_RELAXED,
                               __HIP_MEMORY_SCOPE_AGENT);
    }
}

// ---------------------------------------------------------------------------
// Wave-autonomous fence-free dataflow recurrence.
// 256 blocks = 16 trees x 16 col-blocks, 1 block/CU => co-resident.
// Per level: nodes round-robin'd to waves; each wave runs the full node
// pipeline (poll children -> LDS -> f-MFMA -> hsum -> iou-MFMA -> gates ->
// publish) with NO block barriers; ONE barrier_lds per level for cloc/hloc
// cross-wave visibility. Recurrent weights live in VGPR fragments.
// ---------------------------------------------------------------------------
__global__ __launch_bounds__(256, 1) void tree_k(
    const int* __restrict__ xs, const int* __restrict__ rels,
    const float* __restrict__ emb_W, const float* __restrict__ rel_W,
    const float* __restrict__ W_ix, const float* __restrict__ b_ix,
    const float* __restrict__ W_fx, const float* __restrict__ b_fx,
    const float* __restrict__ W_ox, const float* __restrict__ W_ux,
    const int* __restrict__ child_idx, const int* __restrict__ parent_idx,
    const int* __restrict__ node_height,
    const float* __restrict__ W_ih, const float* __restrict__ b_ih,
    const float* __restrict__ W_fh, const float* __restrict__ b_fh,
    const float* __restrict__ W_oh, const float* __restrict__ W_uh,
    ull* __restrict__ hx, float* __restrict__ poolbuf,
    const float* __restrict__ W_out, const float* __restrict__ b_out,
    float* __restrict__ out)
{
    // ---- dynamic LDS (67584 B, proven size) ----
    extern __shared__ __align__(16) char trans[];
    short* Wbf    = (short*)trans;                  // [4][WC][KP] recurrent W, col-major
    short* hstage = (short*)(trans + 4*WC*KP*2);    // [4 waves][16 rows][KP]; prologue xbf [64][KP]

    // ---- static LDS (~55 KB) ----
    __shared__ float projL[4][SS][WC];       // {ix,fx,ox,ux} own-col slices (x-bias folded)
    __shared__ float cloc[SS][WC+1];
    __shared__ float hloc[SS][WC+1];
    __shared__ short hsrow[4][KP];           // per-wave hsum row (bf16)
    __shared__ float biasF[WC], biasI[WC];
    __shared__ int loff[SS+1], lcur[SS], llist[SS];
    __shared__ int lvoff[NLEV+1], lvcur[NLEV], lvnodes[SS];
    __shared__ int s_maxH;

    const int t    = threadIdx.x;
    const int bid  = blockIdx.x;
    const int xcd  = bid & 7;                // XCD-affine (perf only)
    const int idx  = bid >> 3;
    const int b    = xcd + 8 * (idx >> 4);   // tree
    const int cgp  = idx & 15;               // col group
    const int col0 = cgp * WC;
    const int cc   = t & 15;
    const int rr   = t >> 4;
    const int wv   = t >> 6;                 // wave id
    const int lane = t & 63;
    const int col  = lane & 15;              // MFMA col / A-row index
    const int kg   = lane >> 4;              // MFMA k-slot group

    // ---- P0: stage xs/rels ints; zero counters ----
    if (t < SS) { llist[t] = xs[b*SS + t]; lvnodes[t] = rels[b*SS + t]; lcur[t] = 0; }
    if (t < NLEV) lvcur[t] = 0;
    if (t == 0)   s_maxH = 0;
    __syncthreads();

    // ---- CSR degree atomics + recurrent-W LDS staging + biases + W_x frags ----
    if (t < TE) { int p = parent_idx[b*TE + t] - b*SS; atomicAdd(&lcur[p], 1); }
    if (t < SS) { int hg = node_height[b*SS + t]; atomicAdd(&lvcur[hg], 1); atomicMax(&s_maxH, hg); }
    {
        const float* Wm4[4] = { W_fh, W_ih, W_oh, W_uh };
        for (int m = 0; m < 4; ++m) {
            short* dst = Wbf + (m*WC + cc)*KP;
            const float* src = Wm4[m] + col0 + cc;
            #pragma unroll 4
            for (int kb = 0; kb < 16; ++kb) {
                int k = kb*16 + rr;
                dst[k] = f2bf(src[(long long)k*HH]);
            }
        }
        if (t < WC) { biasF[t] = b_fh[col0+t]; biasI[t] = b_ih[col0+t]; }
    }
    // W_x B-frags in registers (wave wv owns gate wv)
    short8v bfr[8];
    {
        const float* Wxm = (wv==0) ? W_ix : (wv==1) ? W_fx : (wv==2) ? W_ox : W_ux;
        #pragma unroll
        for (int f = 0; f < 8; ++f) {
            #pragma unroll
            for (int j = 0; j < 8; ++j)
                bfr[f][j] = f2bf(Wxm[(long long)(f*32 + kg*8 + j)*HH + col0 + col]);
        }
    }
    const float pbias = (wv==0) ? b_ix[col0+col] : (wv==1) ? b_fx[col0+col] : 0.f;

    // ---- x-gather + proj MFMA in two 64-row halves (xbf overlays hstage) ----
    short* xbf = hstage;   // [64][KP]
    for (int half = 0; half < 2; ++half) {
        __syncthreads();
        #pragma unroll
        for (int r2 = 0; r2 < 16; ++r2) {
            int gr = half*64 + wv*16 + r2;     // global row (node index in tree)
            float4 v;
            if (lane < 48) v = *(const float4*)&emb_W[(long long)llist[gr]*DE + lane*4];
            else           v = *(const float4*)&rel_W[(long long)lvnodes[gr]*DR + (lane-48)*4];
            union { short s[4]; ull u; } pk;
            pk.s[0] = f2bf(v.x); pk.s[1] = f2bf(v.y);
            pk.s[2] = f2bf(v.z); pk.s[3] = f2bf(v.w);
            *(ull*)&xbf[(wv*16 + r2)*KP + lane*4] = pk.u;
        }
        __syncthreads();
        for (int lch = 0; lch < 4; ++lch) {
            f32x4 acc = {0.f,0.f,0.f,0.f};
            const short* ap = xbf + (lch*16 + col)*KP + kg*8;
            #pragma unroll
            for (int f = 0; f < 8; ++f)
                acc = __builtin_amdgcn_mfma_f32_16x16x32_bf16(
                    *(const short8v*)(ap + f*32), bfr[f], acc, 0,0,0);
            #pragma unroll
            for (int r = 0; r < 4; ++r)
                projL[wv][half*64 + lch*16 + kg*4 + r][col] = acc[r] + pbias;
        }
    }
    __syncthreads();

    // ---- recurrent-W register fragments (read once from Wbf) ----
    short8v wfrF[8], wfrI[8], wfrO[8], wfrU[8];
    #pragma unroll
    for (int f = 0; f < 8; ++f) {
        const int o = col*KP + f*32 + kg*8;
        wfrF[f] = *(const short8v*)(Wbf + (0*WC)*KP + o);
        wfrI[f] = *(const short8v*)(Wbf + (1*WC)*KP + o);
        wfrO[f] = *(const short8v*)(Wbf + (2*WC)*KP + o);
        wfrU[f] = *(const short8v*)(Wbf + (3*WC)*KP + o);
    }

    // ---- CSR prefix sums + scatter ----
    if (t == 0) {
        int off = 0;
        for (int i = 0; i < SS; ++i) { int v = lcur[i]; loff[i] = off; lcur[i] = off; off += v; }
        loff[SS] = off;
        off = 0;
        for (int l2 = 0; l2 < NLEV; ++l2) { int v = lvcur[l2]; lvoff[l2] = off; lvcur[l2] = off; off += v; }
        lvoff[NLEV] = off;
    }
    __syncthreads();
    if (t < TE) {
        int e = b*TE + t;
        int p = parent_idx[e] - b*SS;
        int pos = atomicAdd(&lcur[p], 1);
        llist[pos] = child_idx[e] - b*SS;
    }
    if (t < SS) {
        int hg = node_height[b*SS + t];
        int pos = atomicAdd(&lvcur[hg], 1);
        lvnodes[pos] = t;
    }
    __syncthreads();

    // ---- bottom-up levels; ONE barrier per level ----
    short* Hst = hstage + wv*16*KP;          // this wave's staging [16][KP]
    const int mH = s_maxH;
    for (int lev = 0; lev <= mH; ++lev) {
        const int s0 = lvoff[lev], s1 = lvoff[lev+1];

        if (lev == 0) {
            // leaves: 4 per wave-iteration (16-lane groups)
            for (int it = 0; s0 + it*16 + wv*4 < s1; ++it) {
                int j2 = s0 + it*16 + wv*4 + kg;
                if (j2 < s1) {
                    int n = lvnodes[j2];
                    float iv = sigm(projL[0][n][col] + biasI[col]);
                    float ov = sigm(projL[2][n][col]);
                    float uv = tanhf(projL[3][n][col]);
                    float cv = iv * uv;
                    float hv = ov * tanhf(cv);
                    cloc[n][col] = cv; hloc[n][col] = hv;
                    publish4(hv, col, hx + (size_t)(b*SS + n)*64, col0);
                }
            }
        } else {
            int j = s0 + wv;
            ull u[16]; int chr[4];
            int nOff = 0, nE = 0;
            if (j < s1) {                     // ISSUE(first node)
                int n0 = lvnodes[j]; nOff = loff[n0]; nE = loff[n0+1] - nOff;
                int m0 = min(nE, 16);
                #pragma unroll
                for (int rw = 0; rw < 4; ++rw) {
                    int e = kg + rw*4;
                    chr[rw] = (e < m0) ? llist[nOff + e] : -1;
                    if (chr[rw] >= 0) {
                        const ull* sp = hx + (size_t)(b*SS + chr[rw])*64 + col*4;
                        #pragma unroll
                        for (int q = 0; q < 4; ++q) u[rw*4+q] = ld_dev(sp+q);
                    }
                }
            }
            while (j < s1) {
                const int n = lvnodes[j];
                const int off = nOff, E = nE;
                float hs0=0.f, hs1=0.f, hs2=0.f, hs3=0.f, fpart=0.f;
                for (int fr = 0; fr < E; fr += 16) {
                    const int m = min(16, E - fr);
                    if (fr > 0) {             // issue this frame (rare E>16)
                        #pragma unroll
                        for (int rw = 0; rw < 4; ++rw) {
                            int e = kg + rw*4;
                            chr[rw] = (e < m) ? llist[off + fr + e] : -1;
                            if (chr[rw] >= 0) {
                                const ull* sp = hx + (size_t)(b*SS + chr[rw])*64 + col*4;
                                #pragma unroll
                                for (int q = 0; q < 4; ++q) u[rw*4+q] = ld_dev(sp+q);
                            }
                        }
                    }
                    // commit: poll sentinels
                    for (;;) {
                        bool bad = false;
                        #pragma unroll
                        for (int rw = 0; rw < 4; ++rw)
                            if (chr[rw] >= 0) {
                                #pragma unroll
                                for (int q = 0; q < 4; ++q)
                                    bad = bad || (u[rw*4+q] == SENT64);
                            }
                        if (!bad) break;
                        __builtin_amdgcn_s_sleep(1);
                        #pragma unroll
                        for (int rw = 0; rw < 4; ++rw)
                            if (chr[rw] >= 0) {
                                const ull* sp = hx + (size_t)(b*SS + chr[rw])*64 + col*4;
                                #pragma unroll
                                for (int q = 0; q < 4; ++q)
                                    if (u[rw*4+q] == SENT64) u[rw*4+q] = ld_dev(sp+q);
                            }
                    }
                    // stage into LDS
                    #pragma unroll
                    for (int rw = 0; rw < 4; ++rw)
                        if (chr[rw] >= 0) {
                            int e = kg + rw*4;
                            ull* dp = (ull*)&Hst[e*KP + col*16];
                            dp[0]=u[rw*4]; dp[1]=u[rw*4+1]; dp[2]=u[rw*4+2]; dp[3]=u[rw*4+3];
                        }
                    // f-MFMA over frame edges
                    f32x4 fa = {0.f,0.f,0.f,0.f};
                    {
                        const int ro = col*KP + kg*8;
                        #pragma unroll
                        for (int f = 0; f < 8; ++f)
                            fa = __builtin_amdgcn_mfma_f32_16x16x32_bf16(
                                *(const short8v*)(Hst + ro + f*32), wfrF[f], fa, 0,0,0);
                    }
                    // fc partial (D row = kg*4+r = frame edge)
                    #pragma unroll
                    for (int r = 0; r < 4; ++r) {
                        int e = kg*4 + r;
                        if (e < m) {
                            int ch2 = llist[off + fr + e];
                            float fg = sigm(fa[r] + biasF[col] + projL[1][n][col]);
                            fpart += fg * cloc[ch2][col];
                        }
                    }
                    // hsum accumulate: lane sums its 4 cols over frame edges
                    for (int e = 0; e < m; ++e) {
                        union { short s[4]; ull v; } rv;
                        rv.v = *(const ull*)&Hst[e*KP + lane*4];
                        hs0 += bf2f(rv.s[0]); hs1 += bf2f(rv.s[1]);
                        hs2 += bf2f(rv.s[2]); hs3 += bf2f(rv.s[3]);
                    }
                }
                // prefetch next node's child rows (hide poll flight under iou)
                int jn = j + 4;
                if (jn < s1) {
                    int n1 = lvnodes[jn]; nOff = loff[n1]; nE = loff[n1+1] - nOff;
                    int m1 = min(nE, 16);
                    #pragma unroll
                    for (int rw = 0; rw < 4; ++rw) {
                        int e = kg + rw*4;
                        chr[rw] = (e < m1) ? llist[nOff + e] : -1;
                        if (chr[rw] >= 0) {
                            const ull* sp = hx + (size_t)(b*SS + chr[rw])*64 + col*4;
                            #pragma unroll
                            for (int q = 0; q < 4; ++q) u[rw*4+q] = ld_dev(sp+q);
                        }
                    }
                }
                // hsum row (bf16) -> iou MFMAs with shared A-frags
                {
                    union { short s[4]; ull v; } hp;
                    hp.s[0]=f2bf(hs0); hp.s[1]=f2bf(hs1);
                    hp.s[2]=f2bf(hs2); hp.s[3]=f2bf(hs3);
                    *(ull*)&hsrow[wv][lane*4] = hp.v;
                }
                f32x4 ia={0.f,0.f,0.f,0.f}, oa={0.f,0.f,0.f,0.f}, ua={0.f,0.f,0.f,0.f};
                {
                    const short* H = &hsrow[wv][0];
                    #pragma unroll
                    for (int f = 0; f < 8; ++f) {
                        short8v af = *(const short8v*)(H + f*32 + kg*8);
                        ia = __builtin_amdgcn_mfma_f32_16x16x32_bf16(af, wfrI[f], ia, 0,0,0);
                        oa = __builtin_amdgcn_mfma_f32_16x16x32_bf16(af, wfrO[f], oa, 0,0,0);
                        ua = __builtin_amdgcn_mfma_f32_16x16x32_bf16(af, wfrU[f], ua, 0,0,0);
                    }
                }
                fpart += __shfl_xor(fpart, 16);
                fpart += __shfl_xor(fpart, 32);
                if (lane < 16) {
                    float iv = sigm(projL[0][n][lane] + ia[0] + biasI[lane]);
                    float ov = sigm(projL[2][n][lane] + oa[0]);
                    float uv = tanhf(projL[3][n][lane] + ua[0]);
                    float cv = iv*uv + fpart;
                    float hv = ov * tanhf(cv);
                    cloc[n][lane] = cv; hloc[n][lane] = hv;
                    publish4(hv, lane, hx + (size_t)(b*SS + n)*64, col0);
                }
                j = jn;
            }
        }
        barrier_lds();   // cloc/hloc visibility for next level
    }

    // ---- max-pool own columns, exchange via sentinel poolbuf ----
    {
        float* pp = (float*)hstage;          // [16][17] scratch (recurrence done)
        float mx = -3.4e38f;
        for (int s2 = rr; s2 < SS; s2 += RB)
            mx = fmaxf(mx, hloc[s2][cc]);
        pp[rr*17 + cc] = mx;
        __syncthreads();
        if (t < WC) {
            float m2 = pp[0*17 + t];
            #pragma unroll
            for (int r2 = 1; r2 < RB; ++r2) m2 = fmaxf(m2, pp[r2*17 + t]);
            st_devf(&poolbuf[b*HH + col0 + t], m2);
        }
    }
    if (cgp == 0) {
        const int* pb = (const int*)poolbuf + b*HH + t;
        int w = ld_devi(pb);
        while (w == -1) { __builtin_amdgcn_s_sleep(1); w = ld_devi(pb); }
        float* pl = (float*)&hsrow[0][0];    // 256 floats
        pl[t] = __int_as_float(w);
        __syncthreads();
        if (t < LOUT) {
            float acc = b_out[t];
            for (int k = 0; k < HH; ++k)
                acc += pl[k] * W_out[k*LOUT + t];
            out[b*LOUT + t] = acc;
        }
    }
}

// ---------------------------------------------------------------------------
extern "C" void kernel_launch(void* const* d_in, const int* in_sizes, int n_in,
                              void* d_out, int out_size, void* d_ws, size_t ws_size,
                              hipStream_t stream)
{
    const int* xs          = (const int*)d_in[0];
    const int* rels        = (const int*)d_in[1];
    const int* child_idx   = (const int*)d_in[2];
    const int* parent_idx  = (const int*)d_in[3];
    const int* node_height = (const int*)d_in[4];
    // d_in[5] = n_levels (hardcoded NLEV)
    const float* emb_W = (const float*)d_in[6];
    const float* rel_W = (const float*)d_in[7];
    const float* W_ix  = (const float*)d_in[8];
    const float* b_ix  = (const float*)d_in[9];
    const float* W_ih  = (const float*)d_in[10];
    const float* b_ih  = (const float*)d_in[11];
    const float* W_fx  = (const float*)d_in[12];
    const float* b_fx  = (const float*)d_in[13];
    const float* W_fh  = (const float*)d_in[14];
    const float* b_fh  = (const float*)d_in[15];
    const float* W_ox  = (const float*)d_in[16];
    const float* W_oh  = (const float*)d_in[17];
    const float* W_ux  = (const float*)d_in[18];
    const float* W_uh  = (const float*)d_in[19];
    const float* W_out = (const float*)d_in[20];
    const float* b_out = (const float*)d_in[21];

    ull*   hx      = (ull*)d_ws;                              // NN*64 ull = 1 MB
    float* poolbuf = (float*)((char*)d_ws + (size_t)NN*64*8); // BB*HH floats

    fill_k<<<256, 256, 0, stream>>>(hx, (int*)poolbuf);

    const unsigned int shmem = (unsigned int)(8u * WC * KP * 2);   // 67584 B
    tree_k<<<dim3(NT*CB), dim3(256), shmem, stream>>>(
        xs, rels, emb_W, rel_W,
        W_ix, b_ix, W_fx, b_fx, W_ox, W_ux,
        child_idx, parent_idx, node_height,
        W_ih, b_ih, W_fh, b_fh, W_oh, W_uh,
        hx, poolbuf,
        W_out, b_out, (float*)d_out);
}